// Round 3
// baseline (147.370 us; speedup 1.0000x reference)
//
#include <hip/hip_runtime.h>
#include <hip/hip_bf16.h>
#include <math.h>

// Batch-hard triplet loss, B=8192, D=128, fp32 in.
// dist^2[i,j] = rowterm[i] + colterm[j] - 2*dot(e1[i], e2[j])
// sqrt & max/min commute -> track max/min of (colterm - 2*dot); dot on bf16
// matrix cores. Target folded into cpos/cneg (finite +-1e30 sentinels).
//
// R10 vs R9: occupancy round. R9 counters: tile = 46 us, MfmaUtil 13.6%,
// VALUBusy 18%, Occupancy 16%, bank-conflict 3.1M -> latency/barrier-bound
// at 2 waves/SIMD (unified-file regs ~180: 116 arch VGPR + 64 acc AGPR;
// 66 KB LDS also caps 2 blocks/CU). Fix: NO LDS staging at all. B-frags
// read from global (e2b 2 MB = L2-resident; wave pattern = 16 full 64 B
// lines per load). Per-wave output 64x32 (tile 128x64, nTiles 8, SPLITS 16)
// cuts acc to 32 regs -> ~135 total -> 3 waves/SIMD, 12 waves/CU, ZERO
// barriers + zero bank conflicts in the main loop. Prep + reduce tail
// unchanged from R9 (absmax 0).

#define DDIM   128
#define SPLITS 16
#define MARGIN 0.2f
#define EPS    1e-6f
#define SENT   1e30f

typedef unsigned short ushort_t;
typedef __attribute__((ext_vector_type(8))) short short8;
typedef __attribute__((ext_vector_type(4))) float f32x4;
typedef __attribute__((ext_vector_type(4))) unsigned short ushort4_t;

__device__ __forceinline__ ushort_t f2bf(float f) {   // fp32 -> bf16 RNE
    unsigned int u = __float_as_uint(f);
    u = (u + 0x7FFFu + ((u >> 16) & 1u)) >> 16;
    return (ushort_t)u;
}

// ---- kernel 1: bf16 convert + exact fp32 row stats + zero control vars ----
// 8 lanes per row; fully coalesced float4/ushort4. e1b stores bf16(-2*x)
// (exact scale: exp+1 & sign) so MFMA directly yields -2*dot.
__global__ void prep_kernel(const float* __restrict__ e1, const float* __restrict__ e2,
                            const int* __restrict__ target,
                            ushort_t* __restrict__ e1b, ushort_t* __restrict__ e2b,
                            float* __restrict__ rowterm,
                            float* __restrict__ cpos, float* __restrict__ cneg,
                            float* __restrict__ redsum, int* __restrict__ ticket,
                            int* __restrict__ rbTicket, int B) {
    if (blockIdx.x == 0) {
        int t = threadIdx.x;
        if (t < B / 128) rbTicket[t] = 0;               // 64 row-block tickets
        else if (t == 64) { redsum[0] = 0.f; redsum[1] = 0.f; }
        else if (t == 65) *ticket = 0;
    }
    int gr  = blockIdx.x * 32 + (threadIdx.x >> 3);     // 0..2B-1
    int seg = threadIdx.x & 7;
    bool first = gr < B;
    int r = first ? gr : gr - B;
    const float* src = (first ? e1 : e2) + (size_t)r * DDIM;
    ushort_t*    dst = (first ? e1b : e2b) + (size_t)r * DDIM;
    const float sc = first ? -2.f : 1.f;
    float s = 0.f, n = 0.f;
    #pragma unroll
    for (int it = 0; it < 4; ++it) {
        int e0 = (seg + it * 8) * 4;
        float4 v = *(const float4*)(src + e0);
        ushort4_t o;
        o.x = f2bf(sc * v.x); o.y = f2bf(sc * v.y);
        o.z = f2bf(sc * v.z); o.w = f2bf(sc * v.w);
        *(ushort4_t*)(dst + e0) = o;
        s += v.x + v.y + v.z + v.w;
        n += v.x * v.x + v.y * v.y + v.z * v.z + v.w * v.w;
    }
    #pragma unroll
    for (int m = 1; m <= 4; m <<= 1) {                  // 8-lane group reduce
        s += __shfl_xor(s, m, 64);
        n += __shfl_xor(n, m, 64);
    }
    if (seg == 0) {
        if (first) {
            rowterm[r] = n + 2.f * EPS * s + (float)DDIM * EPS * EPS;
        } else {
            float ct = n - 2.f * EPS * s;
            int tg = target[r];
            cpos[r] = (tg == 1) ? ct : -SENT;
            cneg[r] = (tg == 0) ? ct :  SENT;
        }
    }
}

// ---- kernel 2: MFMA tiles straight from L2 + fused masked max/min + tail ----
// grid (B/128, SPLITS=16), block 256 = 4 waves. Per-block 128 rows x 512
// cols as 8 tiles of 128x64. Wave w -> rows (w>>1)*64..+64, cols
// (w&1)*32..+32 of each tile. No LDS, no barriers in the main loop.
__global__ __launch_bounds__(256, 3)
void tile_kernel(const ushort_t* __restrict__ e1b, const ushort_t* __restrict__ e2b,
                 const float* __restrict__ cpos, const float* __restrict__ cneg,
                 const float* __restrict__ rowterm, const int* __restrict__ target,
                 float* __restrict__ pmp, float* __restrict__ nmp,
                 int* __restrict__ rbTicket, float* __restrict__ redsum,
                 int* __restrict__ ticket, float* __restrict__ out, int B) {
    const int tid = threadIdx.x;
    const int w   = tid >> 6;
    const int l   = tid & 63;
    const int lq  = l >> 4;          // quad 0..3
    const int lm  = l & 15;
    const int row0 = blockIdx.x * 128;
    const int colSpan = B / SPLITS;                  // 512
    const int col0 = blockIdx.y * colSpan;
    const int nTiles = colSpan / 64;                 // 8

    const int wr = (w >> 1) * 64;    // wave's row quadrant
    const int wc = (w & 1) * 32;     // wave's col half within 64-col tile

    // A fragments from global (e1b pre-scaled by -2): row = row0+wr+i*16+lm,
    // elems [k4*32 + lq*8, +8). 16 rows x 64 B per load -> full cache lines.
    const ushort_t* aG = e1b + (size_t)(row0 + wr + lm) * DDIM + lq * 8;
    short8 afr[4][4];                // [i][k4] : 64 VGPRs, K=128 resident
    #pragma unroll
    for (int i = 0; i < 4; ++i)
        #pragma unroll
        for (int k4 = 0; k4 < 4; ++k4)
            afr[i][k4] = *(const short8*)(aG + i * 16 * DDIM + k4 * 32);

    // B fragment base: col = col0 + wc + lm (+ j*16 + t*64)
    const ushort_t* bG = e2b + (size_t)(col0 + wc + lm) * DDIM + lq * 8;

    float pm[4][4], nm[4][4];        // [i][r]: local row = wr + i*16 + lq*4 + r
    #pragma unroll
    for (int i = 0; i < 4; ++i)
        #pragma unroll
        for (int r = 0; r < 4; ++r) { pm[i][r] = -SENT; nm[i][r] = SENT; }

    for (int t = 0; t < nTiles; ++t) {
        const ushort_t* bT = bG + (size_t)t * 64 * DDIM;

        f32x4 acc[4][2];
        #pragma unroll
        for (int i = 0; i < 4; ++i)
            #pragma unroll
            for (int j = 0; j < 2; ++j)
                acc[i][j] = (f32x4){0.f, 0.f, 0.f, 0.f};

        #pragma unroll
        for (int k4 = 0; k4 < 4; ++k4) {
            short8 bf[2];
            #pragma unroll
            for (int j = 0; j < 2; ++j)
                bf[j] = *(const short8*)(bT + j * 16 * DDIM + k4 * 32);
            #pragma unroll
            for (int i = 0; i < 4; ++i)
                #pragma unroll
                for (int j = 0; j < 2; ++j)
                    acc[i][j] = __builtin_amdgcn_mfma_f32_16x16x32_bf16(
                                    afr[i][k4], bf[j], acc[i][j], 0, 0, 0);
        }

        // epilogue: acc already = -2*dot. Pair j0/j1 so clang fuses v_max3/min3.
        {
            const int colb = col0 + t * 64 + wc + lm;    // C/D: col = lane&15
            const float cp0 = cpos[colb],      cn0 = cneg[colb];
            const float cp1 = cpos[colb + 16], cn1 = cneg[colb + 16];
            #pragma unroll
            for (int i = 0; i < 4; ++i)
                #pragma unroll
                for (int r = 0; r < 4; ++r) {
                    const float d0 = acc[i][0][r];
                    const float d1 = acc[i][1][r];
                    pm[i][r] = fmaxf(fmaxf(pm[i][r], d0 + cp0), d1 + cp1);
                    nm[i][r] = fminf(fminf(nm[i][r], d0 + cn0), d1 + cn1);
                }
        }
    }

    // intra-wave: reduce across the 16 column-lanes (rows fixed per (lq,r))
    #pragma unroll
    for (int m = 1; m < 16; m <<= 1) {
        #pragma unroll
        for (int i = 0; i < 4; ++i)
            #pragma unroll
            for (int r = 0; r < 4; ++r) {
                pm[i][r] = fmaxf(pm[i][r], __shfl_xor(pm[i][r], m, 64));
                nm[i][r] = fminf(nm[i][r], __shfl_xor(nm[i][r], m, 64));
            }
    }

    // cross-wave: waves (2h, 2h+1) share rows over complementary col halves.
    __shared__ float smP[128], smN[128];
    if ((w & 1) == 1 && lm == 0) {
        #pragma unroll
        for (int i = 0; i < 4; ++i)
            #pragma unroll
            for (int r = 0; r < 4; ++r) {
                int lr = wr + i * 16 + lq * 4 + r;
                smP[lr] = pm[i][r];
                smN[lr] = nm[i][r];
            }
    }
    __syncthreads();
    if ((w & 1) == 0 && lm == 0) {
        #pragma unroll
        for (int i = 0; i < 4; ++i)
            #pragma unroll
            for (int r = 0; r < 4; ++r) {
                int lr  = wr + i * 16 + lq * 4 + r;     // C/D: row = quad*4+reg
                int row = row0 + lr;
                pmp[(size_t)blockIdx.y * B + row] = fmaxf(pm[i][r], smP[lr]);
                nmp[(size_t)blockIdx.y * B + row] = fminf(nm[i][r], smN[lr]);
            }
    }

    // ---- fused reduce tail: last split-block for this row-block finishes ----
    __shared__ int lastrb;
    __syncthreads();                 // partial stores drained (vmcnt0 + barrier)
    if (tid == 0) {
        __threadfence();             // release: writeback this XCD's L2
        int prev = __hip_atomic_fetch_add(&rbTicket[blockIdx.x], 1,
                       __ATOMIC_ACQ_REL, __HIP_MEMORY_SCOPE_AGENT);
        lastrb = (prev == SPLITS - 1);
    }
    __syncthreads();
    if (!lastrb) return;

    float s = 0.f, c = 0.f;
    if (tid < 128) {
        int row = row0 + tid;
        float pmv = -SENT, nmv = SENT;
        #pragma unroll
        for (int sp = 0; sp < SPLITS; ++sp) {   // agent-scope loads: skip stale L1/L2
            pmv = fmaxf(pmv, __hip_atomic_load(&pmp[(size_t)sp * B + row],
                              __ATOMIC_RELAXED, __HIP_MEMORY_SCOPE_AGENT));
            nmv = fminf(nmv, __hip_atomic_load(&nmp[(size_t)sp * B + row],
                              __ATOMIC_RELAXED, __HIP_MEMORY_SCOPE_AGENT));
        }
        float rt = rowterm[row];
        float dp = sqrtf(fmaxf(rt + pmv, 0.f));
        float dn = sqrtf(fmaxf(rt + nmv, 0.f));
        if (target[row] == 1) {
            s = fmaxf(dp - dn + MARGIN, 0.f);
            c = 1.f;
        }
    }
    #pragma unroll
    for (int off = 32; off > 0; off >>= 1) {
        s += __shfl_down(s, off, 64);
        c += __shfl_down(c, off, 64);
    }
    __shared__ float ls[4], lc[4];
    if (l == 0) { ls[w] = s; lc[w] = c; }
    __syncthreads();
    if (tid == 0) {
        float ss = ls[0] + ls[1] + ls[2] + ls[3];
        float cc = lc[0] + lc[1] + lc[2] + lc[3];
        atomicAdd(&redsum[0], ss);
        atomicAdd(&redsum[1], cc);
        __threadfence();
        int done = atomicAdd(ticket, 1);
        if (done == (B / 128) - 1) {            // 64th finisher writes out
            __threadfence();
            float fs = __hip_atomic_load(&redsum[0], __ATOMIC_RELAXED, __HIP_MEMORY_SCOPE_AGENT);
            float fc = __hip_atomic_load(&redsum[1], __ATOMIC_RELAXED, __HIP_MEMORY_SCOPE_AGENT);
            out[0] = fs / fc;
        }
    }
}

extern "C" void kernel_launch(void* const* d_in, const int* in_sizes, int n_in,
                              void* d_out, int out_size, void* d_ws, size_t ws_size,
                              hipStream_t stream) {
    const float* e1     = (const float*)d_in[0];
    const float* e2     = (const float*)d_in[1];
    const int*   target = (const int*)d_in[2];
    float* out = (float*)d_out;
    const int B = in_sizes[2];                       // 8192

    // ws layout: e1b | e2b | rowterm | cpos | cneg | pmp | nmp | redsum | ticket | rbTicket
    char* p = (char*)d_ws;
    ushort_t* e1b  = (ushort_t*)p;   p += (size_t)B * DDIM * 2;   // 2 MB (scaled by -2)
    ushort_t* e2b  = (ushort_t*)p;   p += (size_t)B * DDIM * 2;   // 2 MB
    float* rowterm = (float*)p;      p += (size_t)B * 4;
    float* cpos    = (float*)p;      p += (size_t)B * 4;
    float* cneg    = (float*)p;      p += (size_t)B * 4;
    float* pmp     = (float*)p;      p += (size_t)SPLITS * B * 4; // 512 KB
    float* nmp     = (float*)p;      p += (size_t)SPLITS * B * 4; // 512 KB
    float* redsum  = (float*)p;      p += 2 * 4;
    int*   ticket  = (int*)p;        p += 4;
    int*   rbTicket= (int*)p;        p += (size_t)(B / 128) * 4;

    {   // prep: 8 lanes/row, 32 rows/block -> 2B/32 = 512 blocks
        int blocks = (2 * B) / 32;
        prep_kernel<<<blocks, 256, 0, stream>>>(e1, e2, target, e1b, e2b,
                                                rowterm, cpos, cneg,
                                                redsum, ticket, rbTicket, B);
    }
    {   // 64 row-blocks x 16 col-splits = 1024 blocks, no-LDS, 3-4 blocks/CU
        dim3 grid(B / 128, SPLITS);
        tile_kernel<<<grid, 256, 0, stream>>>(e1b, e2b, cpos, cneg,
                                              rowterm, target, pmp, nmp,
                                              rbTicket, redsum, ticket, out, B);
    }
}

// Round 4
// 119.156 us; speedup vs baseline: 1.2368x; 1.2368x over previous
//
#include <hip/hip_runtime.h>
#include <hip/hip_bf16.h>
#include <math.h>

// Batch-hard triplet loss, B=8192, D=128, fp32 in.
// dist^2[i,j] = rowterm[i] + colterm[j] - 2*dot(e1[i], e2[j])
// sqrt & max/min commute -> track max/min of (colterm - 2*dot); dot on bf16
// matrix cores. Target folded into cpos/cneg (finite +-1e30 sentinels).
//
// R11 vs R10: R10 (global-direct B) regressed to 90 us: 2 waves/SIMD (afr
// spilled to AGPR -> ~176 unified regs) x synchronous L2 loads = exposed
// latency. R9's DMA+LDS was right; its killers were per-tile lockstep
// barriers + 2/SIMD occupancy. R11: block = 128x128 panel (grid 64x64),
// stage the 33 KB B-panel ONCE via width-16 DMA (R9's proven layout), ONE
// barrier, then free-running compute: per wave 64x64 with j-outer acc reuse
// (acc 16 + afr 64 + pm/nm 32 ~ 150 regs) -> __launch_bounds__(256,3):
// 3 waves/SIMD, 3 blocks/CU, blocks self-overlap stage/compute phases.
// MFMA k4-chain identical to R9 -> bit-identical numerics. Fused tail
// reverted (R9 showed fences cost > launch saved); separate reduce kernel.

#define DDIM   128
#define SPLITS 64
#define MARGIN 0.2f
#define EPS    1e-6f
#define SENT   1e30f

#define CHUNK_PITCH 1056           // 1024 B data + 32 B pad
#define WAVE_SPAN   (8 * CHUNK_PITCH)     // 8 chunks (32 rows) per wave
#define TILE_BYTES  (4 * WAVE_SPAN)       // 33792 B per 128x128 bf16 tile

typedef unsigned short ushort_t;
typedef __attribute__((ext_vector_type(8))) short short8;
typedef __attribute__((ext_vector_type(4))) float f32x4;
typedef __attribute__((ext_vector_type(4))) unsigned short ushort4_t;

__device__ __forceinline__ ushort_t f2bf(float f) {   // fp32 -> bf16 RNE
    unsigned int u = __float_as_uint(f);
    u = (u + 0x7FFFu + ((u >> 16) & 1u)) >> 16;
    return (ushort_t)u;
}

__device__ __forceinline__ void g2lds16(const ushort_t* g, void* lds) {
    // wave-uniform lds base; lane i's 16 B land at lds + i*16
    __builtin_amdgcn_global_load_lds(
        (const __attribute__((address_space(1))) unsigned int*)g,
        (__attribute__((address_space(3))) unsigned int*)lds,
        16, 0, 0);
}

// ---- kernel 1: bf16 convert + exact fp32 row stats + zero control vars ----
// 8 lanes per row; fully coalesced float4/ushort4. e1b stores bf16(-2*x)
// (exact scale: exp+1 & sign) so MFMA directly yields -2*dot.
__global__ void prep_kernel(const float* __restrict__ e1, const float* __restrict__ e2,
                            const int* __restrict__ target,
                            ushort_t* __restrict__ e1b, ushort_t* __restrict__ e2b,
                            float* __restrict__ rowterm,
                            float* __restrict__ cpos, float* __restrict__ cneg,
                            float* __restrict__ redsum, int* __restrict__ ticket, int B) {
    if (blockIdx.x == 0) {
        if (threadIdx.x == 0) { redsum[0] = 0.f; redsum[1] = 0.f; }
        else if (threadIdx.x == 1) *ticket = 0;
    }
    int gr  = blockIdx.x * 32 + (threadIdx.x >> 3);     // 0..2B-1
    int seg = threadIdx.x & 7;
    bool first = gr < B;
    int r = first ? gr : gr - B;
    const float* src = (first ? e1 : e2) + (size_t)r * DDIM;
    ushort_t*    dst = (first ? e1b : e2b) + (size_t)r * DDIM;
    const float sc = first ? -2.f : 1.f;
    float s = 0.f, n = 0.f;
    #pragma unroll
    for (int it = 0; it < 4; ++it) {
        int e0 = (seg + it * 8) * 4;
        float4 v = *(const float4*)(src + e0);
        ushort4_t o;
        o.x = f2bf(sc * v.x); o.y = f2bf(sc * v.y);
        o.z = f2bf(sc * v.z); o.w = f2bf(sc * v.w);
        *(ushort4_t*)(dst + e0) = o;
        s += v.x + v.y + v.z + v.w;
        n += v.x * v.x + v.y * v.y + v.z * v.z + v.w * v.w;
    }
    #pragma unroll
    for (int m = 1; m <= 4; m <<= 1) {                  // 8-lane group reduce
        s += __shfl_xor(s, m, 64);
        n += __shfl_xor(n, m, 64);
    }
    if (seg == 0) {
        if (first) {
            rowterm[r] = n + 2.f * EPS * s + (float)DDIM * EPS * EPS;
        } else {
            float ct = n - 2.f * EPS * s;
            int tg = target[r];
            cpos[r] = (tg == 1) ? ct : -SENT;
            cneg[r] = (tg == 0) ? ct :  SENT;
        }
    }
}

// stage a 128x128 bf16 panel via DMA: wave w -> rows [w*32, w*32+32)
__device__ __forceinline__ void stage_tile_dma(const ushort_t* __restrict__ gRow0,
                                               unsigned char* __restrict__ lds,
                                               int w, int l) {
    const ushort_t* g = gRow0 + (size_t)(w * 32) * DDIM + l * 8;
    unsigned char* lp = lds + w * WAVE_SPAN;
    #pragma unroll
    for (int it = 0; it < 8; ++it)
        g2lds16(g + it * 512, lp + it * CHUNK_PITCH);
}

// ---- kernel 2: stage-once B-panel, free-running MFMA + fused max/min ----
// grid (64, 64), block 256 = 4 waves. Block output: 128 rows x 128 cols.
// Wave w: rows (w>>1)*64..+64, cols (w&1)*64..+64. A (K=128) in registers;
// B-panel in LDS staged once; NO barriers in the compute loop.
__global__ __launch_bounds__(256, 3)
void tile_kernel(const ushort_t* __restrict__ e1b, const ushort_t* __restrict__ e2b,
                 const float* __restrict__ cpos, const float* __restrict__ cneg,
                 float* __restrict__ pmp, float* __restrict__ nmp, int B) {
    __shared__ __align__(16) unsigned char Bs[TILE_BYTES];   // 33792 B

    const int tid = threadIdx.x;
    const int w   = tid >> 6;
    const int l   = tid & 63;
    const int lq  = l >> 4;          // quad 0..3
    const int lm  = l & 15;
    const int row0 = blockIdx.x * 128;
    const int col0 = blockIdx.y * 128;

    const int wr = (w >> 1) * 64;    // wave's row half
    const int wc = (w & 1) * 64;     // wave's col half

    // stage B panel (cols col0..col0+127, K=128) once
    stage_tile_dma(e2b + (size_t)col0 * DDIM, Bs, w, l);

    // A fragments straight from global: row = row0+wr+i*16+lm,
    // elems [k4*32 + lq*8, +8). L2-resident (e1b = 2 MB).
    const ushort_t* aG = e1b + (size_t)(row0 + wr + lm) * DDIM + lq * 8;
    short8 afr[4][4];                // [i][k4]: 64 VGPRs, K=128 resident
    #pragma unroll
    for (int i = 0; i < 4; ++i)
        #pragma unroll
        for (int k4 = 0; k4 < 4; ++k4)
            afr[i][k4] = *(const short8*)(aG + i * 16 * DDIM + k4 * 32);

    // fragment row R = wc + j*16 + lm; byte addr =
    //   (R>>2)*1056 + (R&3)*256 + lq*16 + k4*64  (laneBase lane-constant)
    const unsigned char* bLane = Bs + ((wc >> 2) + (lm >> 2)) * CHUNK_PITCH
                                    + (lm & 3) * 256 + lq * 16;

    float pm[4][4], nm[4][4];        // [i][r]: local row = wr + i*16 + lq*4 + r
    #pragma unroll
    for (int i = 0; i < 4; ++i)
        #pragma unroll
        for (int r = 0; r < 4; ++r) { pm[i][r] = -SENT; nm[i][r] = SENT; }

    __syncthreads();                 // drains DMA; B panel + afr visible

    // j-outer: acc reuse (16 regs live) -> ~150 total regs -> 3 waves/SIMD
    #pragma unroll
    for (int j = 0; j < 4; ++j) {
        const unsigned char* blj = bLane + j * (4 * CHUNK_PITCH);

        f32x4 acc[4];
        #pragma unroll
        for (int i = 0; i < 4; ++i) acc[i] = (f32x4){0.f, 0.f, 0.f, 0.f};

        #pragma unroll
        for (int k4 = 0; k4 < 4; ++k4) {
            const short8 bf = *(const short8*)(blj + k4 * 64);
            #pragma unroll
            for (int i = 0; i < 4; ++i)
                acc[i] = __builtin_amdgcn_mfma_f32_16x16x32_bf16(
                             afr[i][k4], bf, acc[i], 0, 0, 0);
        }

        // epilogue: acc already = -2*dot (e1b pre-scaled); add colterm, track
        const int col = col0 + wc + j * 16 + lm;     // C/D: col = lane&15
        const float cp = cpos[col];
        const float cn = cneg[col];
        #pragma unroll
        for (int i = 0; i < 4; ++i)
            #pragma unroll
            for (int r = 0; r < 4; ++r) {
                const float d = acc[i][r];
                pm[i][r] = fmaxf(pm[i][r], d + cp);
                nm[i][r] = fminf(nm[i][r], d + cn);
            }
    }

    // intra-wave: reduce across the 16 column-lanes (rows fixed per (lq,r))
    #pragma unroll
    for (int m = 1; m < 16; m <<= 1) {
        #pragma unroll
        for (int i = 0; i < 4; ++i)
            #pragma unroll
            for (int r = 0; r < 4; ++r) {
                pm[i][r] = fmaxf(pm[i][r], __shfl_xor(pm[i][r], m, 64));
                nm[i][r] = fminf(nm[i][r], __shfl_xor(nm[i][r], m, 64));
            }
    }

    // cross-wave: pairs (0,1),(2,3) share rows over complementary col halves.
    // Combine via LDS overlay on Bs (done with B reads after the barrier).
    float* smP = (float*)Bs;               // [128]
    float* smN = smP + 128;                // [128]
    __syncthreads();                       // all waves done reading Bs
    if ((w & 1) == 1 && lm == 0) {
        #pragma unroll
        for (int i = 0; i < 4; ++i)
            #pragma unroll
            for (int r = 0; r < 4; ++r) {
                int lr = wr + i * 16 + lq * 4 + r;
                smP[lr] = pm[i][r];
                smN[lr] = nm[i][r];
            }
    }
    __syncthreads();
    if ((w & 1) == 0 && lm == 0) {
        #pragma unroll
        for (int i = 0; i < 4; ++i)
            #pragma unroll
            for (int r = 0; r < 4; ++r) {
                int lr = wr + i * 16 + lq * 4 + r;   // C/D: row = quad*4+reg
                smP[lr] = fmaxf(pm[i][r], smP[lr]);
                smN[lr] = fminf(nm[i][r], smN[lr]);
            }
    }
    __syncthreads();
    if (tid < 128) {                       // coalesced partial store
        pmp[(size_t)blockIdx.y * B + row0 + tid] = smP[tid];
        nmp[(size_t)blockIdx.y * B + row0 + tid] = smN[tid];
    }
}

// ---- kernel 3: per-row combine + hinge; atomic partials; last block divides ----
__global__ void reduce_kernel(const float* __restrict__ pmp, const float* __restrict__ nmp,
                              const float* __restrict__ rowterm, const int* __restrict__ target,
                              float* __restrict__ redsum, int* __restrict__ ticket,
                              float* __restrict__ out, int B) {
    int row = blockIdx.x * blockDim.x + threadIdx.x;    // 32 x 256 = 8192
    float s = 0.f, c = 0.f;
    {
        float pmv = -SENT, nmv = SENT;
        #pragma unroll 8
        for (int sp = 0; sp < SPLITS; ++sp) {
            pmv = fmaxf(pmv, pmp[(size_t)sp * B + row]);
            nmv = fminf(nmv, nmp[(size_t)sp * B + row]);
        }
        float rt = rowterm[row];
        float dp = sqrtf(fmaxf(rt + pmv, 0.f));
        float dn = sqrtf(fmaxf(rt + nmv, 0.f));
        if (target[row] == 1) {
            s = fmaxf(dp - dn + MARGIN, 0.f);
            c = 1.f;
        }
    }
    #pragma unroll
    for (int off = 32; off > 0; off >>= 1) {
        s += __shfl_down(s, off, 64);
        c += __shfl_down(c, off, 64);
    }
    __shared__ float ls[4], lc[4];
    int wv = threadIdx.x >> 6, ln = threadIdx.x & 63;
    if (ln == 0) { ls[wv] = s; lc[wv] = c; }
    __syncthreads();
    if (threadIdx.x == 0) {
        float ss = ls[0] + ls[1] + ls[2] + ls[3];
        float cc = lc[0] + lc[1] + lc[2] + lc[3];
        atomicAdd(&redsum[0], ss);
        atomicAdd(&redsum[1], cc);
        __threadfence();
        int done = atomicAdd(ticket, 1);
        if (done == (int)gridDim.x - 1) {
            __threadfence();
            float fs = __hip_atomic_load(&redsum[0], __ATOMIC_RELAXED, __HIP_MEMORY_SCOPE_AGENT);
            float fc = __hip_atomic_load(&redsum[1], __ATOMIC_RELAXED, __HIP_MEMORY_SCOPE_AGENT);
            out[0] = fs / fc;
        }
    }
}

extern "C" void kernel_launch(void* const* d_in, const int* in_sizes, int n_in,
                              void* d_out, int out_size, void* d_ws, size_t ws_size,
                              hipStream_t stream) {
    const float* e1     = (const float*)d_in[0];
    const float* e2     = (const float*)d_in[1];
    const int*   target = (const int*)d_in[2];
    float* out = (float*)d_out;
    const int B = in_sizes[2];                       // 8192

    // ws layout: e1b | e2b | rowterm | cpos | cneg | pmp | nmp | redsum | ticket
    char* p = (char*)d_ws;
    ushort_t* e1b  = (ushort_t*)p;   p += (size_t)B * DDIM * 2;   // 2 MB (scaled by -2)
    ushort_t* e2b  = (ushort_t*)p;   p += (size_t)B * DDIM * 2;   // 2 MB
    float* rowterm = (float*)p;      p += (size_t)B * 4;
    float* cpos    = (float*)p;      p += (size_t)B * 4;
    float* cneg    = (float*)p;      p += (size_t)B * 4;
    float* pmp     = (float*)p;      p += (size_t)SPLITS * B * 4; // 2 MB
    float* nmp     = (float*)p;      p += (size_t)SPLITS * B * 4; // 2 MB
    float* redsum  = (float*)p;      p += 2 * 4;
    int*   ticket  = (int*)p;

    {   // prep: 8 lanes/row, 32 rows/block -> 2B/32 = 512 blocks
        int blocks = (2 * B) / 32;
        prep_kernel<<<blocks, 256, 0, stream>>>(e1, e2, target, e1b, e2b,
                                                rowterm, cpos, cneg,
                                                redsum, ticket, B);
    }
    {   // 64 row-blocks x 64 col-blocks = 4096 blocks; 34 KB LDS, 3 blocks/CU
        dim3 grid(B / 128, B / 128);
        tile_kernel<<<grid, 256, 0, stream>>>(e1b, e2b, cpos, cneg, pmp, nmp, B);
    }
    reduce_kernel<<<32, 256, 0, stream>>>(pmp, nmp, rowterm, target,
                                          redsum, ticket, out, B);
}

// Round 5
// 91.108 us; speedup vs baseline: 1.6175x; 1.3079x over previous
//
#include <hip/hip_runtime.h>
#include <hip/hip_bf16.h>
#include <math.h>

// Batch-hard triplet loss, B=8192, D=128, fp32 in.
// dist^2[i,j] = rowterm[i] + colterm[j] - 2*dot(e1[i], e2[j])
// sqrt & max/min commute -> track max/min of (colterm - 2*dot); dot on bf16
// matrix cores. Target folded into cpos/cneg (finite +-1e30 sentinels).
//
// R12: synthesis of R8-R11 lessons. R9: lockstep + 2/SIMD = 46us. R10: sync
// global B loads = 90us. R11: 4096 tiny blocks -> per-block serial prologue/
// epilogue dominates = 55us (all pipes <30%). R12 structure:
//  - block = 128 rows x 1024 cols (512 blocks, SPLITS=8): epilogue reduce
//    amortized over 16 panels (runs 512x, not 4096x).
//  - 64-col B panels DMA'd into LDS, double-buffered (2x16.9 KB), stage
//    issued BEFORE compute, ONE barrier per panel -> drain hidden.
//  - per wave 64x32/panel, accA/accB reuse: ~160 regs -> 3 waves/SIMD
//    (__launch_bounds__(256,3)); LDS 33.8 KB -> not the occupancy cap.
//  - bank-conflict fix: 16B-slot low-2-bits XOR row&3, applied on DMA
//    source (per-lane global addr permute; same cache lines) and ds_read
//    addr (lq -> lq^(lm&3)). 4-way -> 2-way (free). Pure permutation ->
//    bit-identical numerics.

#define DDIM   128
#define SPLITS 8
#define MARGIN 0.2f
#define EPS    1e-6f
#define SENT   1e30f

#define CHUNK_PITCH  1056          // 1024 B data (4 rows x 256 B) + 32 B pad
#define PANEL_CHUNKS 16            // 64 rows per panel
#define PANEL_BYTES  (PANEL_CHUNKS * CHUNK_PITCH)   // 16896 B

typedef unsigned short ushort_t;
typedef __attribute__((ext_vector_type(8))) short short8;
typedef __attribute__((ext_vector_type(4))) float f32x4;
typedef __attribute__((ext_vector_type(4))) unsigned short ushort4_t;

__device__ __forceinline__ ushort_t f2bf(float f) {   // fp32 -> bf16 RNE
    unsigned int u = __float_as_uint(f);
    u = (u + 0x7FFFu + ((u >> 16) & 1u)) >> 16;
    return (ushort_t)u;
}

__device__ __forceinline__ void g2lds16(const ushort_t* g, void* lds) {
    // wave-uniform lds base; lane i's 16 B land at lds + i*16
    __builtin_amdgcn_global_load_lds(
        (const __attribute__((address_space(1))) unsigned int*)g,
        (__attribute__((address_space(3))) unsigned int*)lds,
        16, 0, 0);
}

// ---- kernel 1: bf16 convert + exact fp32 row stats + zero control vars ----
// 8 lanes per row; fully coalesced float4/ushort4. e1b stores bf16(-2*x)
// (exact scale: exp+1 & sign) so MFMA directly yields -2*dot.
__global__ void prep_kernel(const float* __restrict__ e1, const float* __restrict__ e2,
                            const int* __restrict__ target,
                            ushort_t* __restrict__ e1b, ushort_t* __restrict__ e2b,
                            float* __restrict__ rowterm,
                            float* __restrict__ cpos, float* __restrict__ cneg,
                            float* __restrict__ redsum, int* __restrict__ ticket, int B) {
    if (blockIdx.x == 0) {
        if (threadIdx.x == 0) { redsum[0] = 0.f; redsum[1] = 0.f; }
        else if (threadIdx.x == 1) *ticket = 0;
    }
    int gr  = blockIdx.x * 32 + (threadIdx.x >> 3);     // 0..2B-1
    int seg = threadIdx.x & 7;
    bool first = gr < B;
    int r = first ? gr : gr - B;
    const float* src = (first ? e1 : e2) + (size_t)r * DDIM;
    ushort_t*    dst = (first ? e1b : e2b) + (size_t)r * DDIM;
    const float sc = first ? -2.f : 1.f;
    float s = 0.f, n = 0.f;
    #pragma unroll
    for (int it = 0; it < 4; ++it) {
        int e0 = (seg + it * 8) * 4;
        float4 v = *(const float4*)(src + e0);
        ushort4_t o;
        o.x = f2bf(sc * v.x); o.y = f2bf(sc * v.y);
        o.z = f2bf(sc * v.z); o.w = f2bf(sc * v.w);
        *(ushort4_t*)(dst + e0) = o;
        s += v.x + v.y + v.z + v.w;
        n += v.x * v.x + v.y * v.y + v.z * v.z + v.w * v.w;
    }
    #pragma unroll
    for (int m = 1; m <= 4; m <<= 1) {                  // 8-lane group reduce
        s += __shfl_xor(s, m, 64);
        n += __shfl_xor(n, m, 64);
    }
    if (seg == 0) {
        if (first) {
            rowterm[r] = n + 2.f * EPS * s + (float)DDIM * EPS * EPS;
        } else {
            float ct = n - 2.f * EPS * s;
            int tg = target[r];
            cpos[r] = (tg == 1) ? ct : -SENT;
            cneg[r] = (tg == 0) ? ct :  SENT;
        }
    }
}

// stage a 64-row bf16 panel (rows = cols of C) via DMA. Wave w stages rows
// [w*16, w*16+16) = chunks 4w..4w+3. Source slot pre-swizzled: slot low-2
// bits XOR chunk-local row, so linear DMA lands the swizzled layout.
__device__ __forceinline__ void stage_panel(const ushort_t* __restrict__ rowBase,
                                            unsigned char* __restrict__ lds,
                                            int w, int l, int sl) {
    const ushort_t* g = rowBase + (size_t)(w * 16 + (l >> 4)) * DDIM + sl * 8;
    unsigned char* lp = lds + (w * 4) * CHUNK_PITCH;
    #pragma unroll
    for (int it = 0; it < 4; ++it)
        g2lds16(g + it * 4 * DDIM, lp + it * CHUNK_PITCH);
}

// ---- kernel 2: streamed 64-col panels, MFMA + fused masked max/min ------
// grid (B/128, SPLITS=8), block 256 = 4 waves. Block: 128 rows x 1024 cols
// as 16 panels of 64 cols, double-buffered. Wave w: rows (w>>1)*64..+64,
// cols (w&1)*32..+32 of each panel. A (K=128) in registers from L2.
__global__ __launch_bounds__(256, 3)
void tile_kernel(const ushort_t* __restrict__ e1b, const ushort_t* __restrict__ e2b,
                 const float* __restrict__ cpos, const float* __restrict__ cneg,
                 float* __restrict__ pmp, float* __restrict__ nmp, int B) {
    __shared__ __align__(16) unsigned char Bs[2][PANEL_BYTES];   // 33792 B

    const int tid = threadIdx.x;
    const int w   = tid >> 6;
    const int l   = tid & 63;
    const int lq  = l >> 4;          // quad 0..3
    const int lm  = l & 15;
    const int row0 = blockIdx.x * 128;
    const int col0 = blockIdx.y * 1024;
    const int nPanels = 16;

    const int wr = (w >> 1) * 64;    // wave's row half
    const int wc = (w & 1) * 32;     // wave's col half within 64-col panel

    // staging source-slot swizzle: slot = (l&15) with low2 ^= (l>>4)
    const int sl = (l & 12) | ((l ^ (l >> 4)) & 3);

    // stage panel 0
    stage_panel(e2b + (size_t)col0 * DDIM, Bs[0], w, l, sl);

    // A fragments straight from global: row = row0+wr+i*16+lm,
    // elems [k4*32 + lq*8, +8). L2-resident (e1b = 2 MB, pre-scaled by -2).
    const ushort_t* aG = e1b + (size_t)(row0 + wr + lm) * DDIM + lq * 8;
    short8 afr[4][4];                // [i][k4]: 64 regs, K=128 resident
    #pragma unroll
    for (int i = 0; i < 4; ++i)
        #pragma unroll
        for (int k4 = 0; k4 < 4; ++k4)
            afr[i][k4] = *(const short8*)(aG + i * 16 * DDIM + k4 * 32);

    // B fragment read base: row R = wc + j*16 + lm; byte addr =
    //   (R>>2)*1056 + (R&3)*256 + (k4*4 + (lq^(R&3)))*16
    // (lane-constant base; + j*4*1056 + k4*64). lq^(lm&3) = swizzle inverse.
    const unsigned char* bLane = &Bs[0][0]
        + ((wc >> 2) + (lm >> 2)) * CHUNK_PITCH
        + (lm & 3) * 256 + ((lq ^ (lm & 3)) * 16);

    float pm[4][4], nm[4][4];        // [i][r]: local row = wr + i*16 + lq*4 + r
    #pragma unroll
    for (int i = 0; i < 4; ++i)
        #pragma unroll
        for (int r = 0; r < 4; ++r) { pm[i][r] = -SENT; nm[i][r] = SENT; }

    __syncthreads();                 // drains panel-0 DMA

    for (int p = 0; p < nPanels; ++p) {
        // issue next panel's DMA FIRST; lands under this panel's compute
        if (p + 1 < nPanels)
            stage_panel(e2b + (size_t)(col0 + (p + 1) * 64) * DDIM,
                        Bs[(p + 1) & 1], w, l, sl);

        const unsigned char* bl = bLane + (p & 1) * PANEL_BYTES;

        f32x4 accA[4], accB[4];      // j=0 / j=1 accumulators (32 regs)
        #pragma unroll
        for (int i = 0; i < 4; ++i) {
            accA[i] = (f32x4){0.f, 0.f, 0.f, 0.f};
            accB[i] = (f32x4){0.f, 0.f, 0.f, 0.f};
        }

        #pragma unroll
        for (int k4 = 0; k4 < 4; ++k4) {
            const short8 b0 = *(const short8*)(bl + k4 * 64);
            const short8 b1 = *(const short8*)(bl + 4 * CHUNK_PITCH + k4 * 64);
            #pragma unroll
            for (int i = 0; i < 4; ++i)
                accA[i] = __builtin_amdgcn_mfma_f32_16x16x32_bf16(
                              afr[i][k4], b0, accA[i], 0, 0, 0);
            #pragma unroll
            for (int i = 0; i < 4; ++i)
                accB[i] = __builtin_amdgcn_mfma_f32_16x16x32_bf16(
                              afr[i][k4], b1, accB[i], 0, 0, 0);
        }

        // epilogue: acc = -2*dot. Pair j0/j1 so clang fuses v_max3/v_min3.
        {
            const int colb = col0 + p * 64 + wc + lm;    // C/D: col = lane&15
            const float cp0 = cpos[colb],      cn0 = cneg[colb];
            const float cp1 = cpos[colb + 16], cn1 = cneg[colb + 16];
            #pragma unroll
            for (int i = 0; i < 4; ++i)
                #pragma unroll
                for (int r = 0; r < 4; ++r) {
                    const float d0 = accA[i][r];
                    const float d1 = accB[i][r];
                    pm[i][r] = fmaxf(fmaxf(pm[i][r], d0 + cp0), d1 + cp1);
                    nm[i][r] = fminf(fminf(nm[i][r], d0 + cn0), d1 + cn1);
                }
        }

        __syncthreads();   // all waves done with Bs[p&1]; drains stage(p+1)
    }

    // intra-wave: reduce across the 16 column-lanes (rows fixed per (lq,r))
    #pragma unroll
    for (int m = 1; m < 16; m <<= 1) {
        #pragma unroll
        for (int i = 0; i < 4; ++i)
            #pragma unroll
            for (int r = 0; r < 4; ++r) {
                pm[i][r] = fmaxf(pm[i][r], __shfl_xor(pm[i][r], m, 64));
                nm[i][r] = fminf(nm[i][r], __shfl_xor(nm[i][r], m, 64));
            }
    }

    // cross-wave: pairs (0,1),(2,3) share rows over complementary col halves.
    // Combine via LDS overlay on Bs (loop's last barrier already passed).
    float* smP = (float*)Bs;               // [128]
    float* smN = smP + 128;                // [128]
    if ((w & 1) == 1 && lm == 0) {
        #pragma unroll
        for (int i = 0; i < 4; ++i)
            #pragma unroll
            for (int r = 0; r < 4; ++r) {
                int lr = wr + i * 16 + lq * 4 + r;
                smP[lr] = pm[i][r];
                smN[lr] = nm[i][r];
            }
    }
    __syncthreads();
    if ((w & 1) == 0 && lm == 0) {
        #pragma unroll
        for (int i = 0; i < 4; ++i)
            #pragma unroll
            for (int r = 0; r < 4; ++r) {
                int lr = wr + i * 16 + lq * 4 + r;   // C/D: row = quad*4+reg
                smP[lr] = fmaxf(pm[i][r], smP[lr]);
                smN[lr] = fminf(nm[i][r], smN[lr]);
            }
    }
    __syncthreads();
    if (tid < 128) {                       // coalesced partial store
        pmp[(size_t)blockIdx.y * B + row0 + tid] = smP[tid];
        nmp[(size_t)blockIdx.y * B + row0 + tid] = smN[tid];
    }
}

// ---- kernel 3: per-row combine + hinge; atomic partials; last block divides ----
__global__ void reduce_kernel(const float* __restrict__ pmp, const float* __restrict__ nmp,
                              const float* __restrict__ rowterm, const int* __restrict__ target,
                              float* __restrict__ redsum, int* __restrict__ ticket,
                              float* __restrict__ out, int B) {
    int row = blockIdx.x * blockDim.x + threadIdx.x;    // 32 x 256 = 8192
    float s = 0.f, c = 0.f;
    {
        float pmv = -SENT, nmv = SENT;
        #pragma unroll
        for (int sp = 0; sp < SPLITS; ++sp) {
            pmv = fmaxf(pmv, pmp[(size_t)sp * B + row]);
            nmv = fminf(nmv, nmp[(size_t)sp * B + row]);
        }
        float rt = rowterm[row];
        float dp = sqrtf(fmaxf(rt + pmv, 0.f));
        float dn = sqrtf(fmaxf(rt + nmv, 0.f));
        if (target[row] == 1) {
            s = fmaxf(dp - dn + MARGIN, 0.f);
            c = 1.f;
        }
    }
    #pragma unroll
    for (int off = 32; off > 0; off >>= 1) {
        s += __shfl_down(s, off, 64);
        c += __shfl_down(c, off, 64);
    }
    __shared__ float ls[4], lc[4];
    int wv = threadIdx.x >> 6, ln = threadIdx.x & 63;
    if (ln == 0) { ls[wv] = s; lc[wv] = c; }
    __syncthreads();
    if (threadIdx.x == 0) {
        float ss = ls[0] + ls[1] + ls[2] + ls[3];
        float cc = lc[0] + lc[1] + lc[2] + lc[3];
        atomicAdd(&redsum[0], ss);
        atomicAdd(&redsum[1], cc);
        __threadfence();
        int done = atomicAdd(ticket, 1);
        if (done == (int)gridDim.x - 1) {
            __threadfence();
            float fs = __hip_atomic_load(&redsum[0], __ATOMIC_RELAXED, __HIP_MEMORY_SCOPE_AGENT);
            float fc = __hip_atomic_load(&redsum[1], __ATOMIC_RELAXED, __HIP_MEMORY_SCOPE_AGENT);
            out[0] = fs / fc;
        }
    }
}

extern "C" void kernel_launch(void* const* d_in, const int* in_sizes, int n_in,
                              void* d_out, int out_size, void* d_ws, size_t ws_size,
                              hipStream_t stream) {
    const float* e1     = (const float*)d_in[0];
    const float* e2     = (const float*)d_in[1];
    const int*   target = (const int*)d_in[2];
    float* out = (float*)d_out;
    const int B = in_sizes[2];                       // 8192

    // ws layout: e1b | e2b | rowterm | cpos | cneg | pmp | nmp | redsum | ticket
    char* p = (char*)d_ws;
    ushort_t* e1b  = (ushort_t*)p;   p += (size_t)B * DDIM * 2;   // 2 MB (scaled by -2)
    ushort_t* e2b  = (ushort_t*)p;   p += (size_t)B * DDIM * 2;   // 2 MB
    float* rowterm = (float*)p;      p += (size_t)B * 4;
    float* cpos    = (float*)p;      p += (size_t)B * 4;
    float* cneg    = (float*)p;      p += (size_t)B * 4;
    float* pmp     = (float*)p;      p += (size_t)SPLITS * B * 4; // 256 KB
    float* nmp     = (float*)p;      p += (size_t)SPLITS * B * 4; // 256 KB
    float* redsum  = (float*)p;      p += 2 * 4;
    int*   ticket  = (int*)p;

    {   // prep: 8 lanes/row, 32 rows/block -> 2B/32 = 512 blocks
        int blocks = (2 * B) / 32;
        prep_kernel<<<blocks, 256, 0, stream>>>(e1, e2, target, e1b, e2b,
                                                rowterm, cpos, cneg,
                                                redsum, ticket, B);
    }
    {   // 64 row-blocks x 8 col-splits = 512 blocks; 33.8 KB LDS, 3 waves/SIMD
        dim3 grid(B / 128, SPLITS);
        tile_kernel<<<grid, 256, 0, stream>>>(e1b, e2b, cpos, cneg, pmp, nmp, B);
    }
    reduce_kernel<<<32, 256, 0, stream>>>(pmp, nmp, rowterm, target,
                                          redsum, ticket, out, B);
}

// Round 7
// 89.992 us; speedup vs baseline: 1.6376x; 1.0124x over previous
//
#include <hip/hip_runtime.h>
#include <hip/hip_bf16.h>
#include <math.h>

// Batch-hard triplet loss, B=8192, D=128, fp32 in.
// dist^2[i,j] = rowterm[i] + colterm[j] - 2*dot(e1[i], e2[j])
// sqrt & max/min commute -> track max/min of (colterm - 2*dot); dot on bf16
// matrix cores. Target folded into cpos/cneg (finite +-1e30 sentinels).
//
// R14 vs R13: R13 raced (absmax 1.2e16): per-wave vmcnt(4) only proves THIS
// wave's stage(p) landed, but wave 0 reads rows 16..31 staged by wave 1 ->
// read-before-land. Fix = m201's exact phase order, wait-THEN-barrier:
//   [p>0] s_barrier              // WAR: all waves done reading panel p-1
//   issue stage(p+1)             // queue [stage(p):4, stage(p+1):4]
//   s_waitcnt vmcnt(4)           // own stage(p) retired; p+1 in flight
//   s_barrier                    // RAW: every wave retired ITS stage(p)
//   compute(p)                   //  -> whole panel p resident
// stage(p+1) still crosses both barriers with a full panel of compute to
// land under (the R12 drain-stall removal is preserved); extra barrier
// ~100 cyc vs the ~3.5k cyc vmcnt(0) drain it replaces. cpos/cneg live in
// LDS so the vmcnt ledger holds exactly the stage DMAs. Same swizzled
// layout, same MFMA order as R12 -> bit-identical numerics (absmax 0).

#define DDIM   128
#define SPLITS 8
#define MARGIN 0.2f
#define EPS    1e-6f
#define SENT   1e30f

#define CHUNK_PITCH  1056          // 1024 B data (4 rows x 256 B) + 32 B pad
#define PANEL_CHUNKS 16            // 64 rows per panel
#define PANEL_BYTES  (PANEL_CHUNKS * CHUNK_PITCH)   // 16896 B
#define CPCN_BYTES   (2048 * 4)                     // 1024 cp + 1024 cn floats

typedef unsigned short ushort_t;
typedef __attribute__((ext_vector_type(8))) short short8;
typedef __attribute__((ext_vector_type(4))) float f32x4;
typedef __attribute__((ext_vector_type(4))) unsigned short ushort4_t;

__device__ __forceinline__ ushort_t f2bf(float f) {   // fp32 -> bf16 RNE
    unsigned int u = __float_as_uint(f);
    u = (u + 0x7FFFu + ((u >> 16) & 1u)) >> 16;
    return (ushort_t)u;
}

__device__ __forceinline__ void g2lds16(const void* g, void* lds) {
    // per-lane global src; wave-uniform lds base, lane i's 16 B at lds+i*16
    __builtin_amdgcn_global_load_lds(
        (const __attribute__((address_space(1))) unsigned int*)g,
        (__attribute__((address_space(3))) unsigned int*)lds,
        16, 0, 0);
}

// ---- kernel 1: bf16 convert + exact fp32 row stats + zero control vars ----
// 8 lanes per row; fully coalesced float4/ushort4. e1b stores bf16(-2*x)
// (exact scale: exp+1 & sign) so MFMA directly yields -2*dot.
__global__ void prep_kernel(const float* __restrict__ e1, const float* __restrict__ e2,
                            const int* __restrict__ target,
                            ushort_t* __restrict__ e1b, ushort_t* __restrict__ e2b,
                            float* __restrict__ rowterm,
                            float* __restrict__ cpos, float* __restrict__ cneg,
                            float* __restrict__ redsum, int* __restrict__ ticket, int B) {
    if (blockIdx.x == 0) {
        if (threadIdx.x == 0) { redsum[0] = 0.f; redsum[1] = 0.f; }
        else if (threadIdx.x == 1) *ticket = 0;
    }
    int gr  = blockIdx.x * 32 + (threadIdx.x >> 3);     // 0..2B-1
    int seg = threadIdx.x & 7;
    bool first = gr < B;
    int r = first ? gr : gr - B;
    const float* src = (first ? e1 : e2) + (size_t)r * DDIM;
    ushort_t*    dst = (first ? e1b : e2b) + (size_t)r * DDIM;
    const float sc = first ? -2.f : 1.f;
    float s = 0.f, n = 0.f;
    #pragma unroll
    for (int it = 0; it < 4; ++it) {
        int e0 = (seg + it * 8) * 4;
        float4 v = *(const float4*)(src + e0);
        ushort4_t o;
        o.x = f2bf(sc * v.x); o.y = f2bf(sc * v.y);
        o.z = f2bf(sc * v.z); o.w = f2bf(sc * v.w);
        *(ushort4_t*)(dst + e0) = o;
        s += v.x + v.y + v.z + v.w;
        n += v.x * v.x + v.y * v.y + v.z * v.z + v.w * v.w;
    }
    #pragma unroll
    for (int m = 1; m <= 4; m <<= 1) {                  // 8-lane group reduce
        s += __shfl_xor(s, m, 64);
        n += __shfl_xor(n, m, 64);
    }
    if (seg == 0) {
        if (first) {
            rowterm[r] = n + 2.f * EPS * s + (float)DDIM * EPS * EPS;
        } else {
            float ct = n - 2.f * EPS * s;
            int tg = target[r];
            cpos[r] = (tg == 1) ? ct : -SENT;
            cneg[r] = (tg == 0) ? ct :  SENT;
        }
    }
}

// stage a 64-row bf16 panel (rows = cols of C) via DMA. Wave w stages rows
// [w*16, w*16+16) = chunks 4w..4w+3. Source slot pre-swizzled: slot low-2
// bits XOR chunk-local row, so linear DMA lands the swizzled layout.
__device__ __forceinline__ void stage_panel(const ushort_t* __restrict__ rowBase,
                                            unsigned char* __restrict__ lds,
                                            int w, int l, int sl) {
    const ushort_t* g = rowBase + (size_t)(w * 16 + (l >> 4)) * DDIM + sl * 8;
    unsigned char* lp = lds + (w * 4) * CHUNK_PITCH;
    #pragma unroll
    for (int it = 0; it < 4; ++it)
        g2lds16(g + it * 4 * DDIM, lp + it * CHUNK_PITCH);
}

// ---- kernel 2: streamed 64-col panels, counted-vmcnt pipeline -----------
// grid (B/128, SPLITS=8), block 256 = 4 waves. Block: 128 rows x 1024 cols
// as 16 panels of 64 cols, double-buffered. Wave w: rows (w>>1)*64..+64,
// cols (w&1)*32..+32 of each panel. A (K=128) in registers from L2.
__global__ __launch_bounds__(256, 3)
void tile_kernel(const ushort_t* __restrict__ e1b, const ushort_t* __restrict__ e2b,
                 const float* __restrict__ cpos, const float* __restrict__ cneg,
                 float* __restrict__ pmp, float* __restrict__ nmp, int B) {
    __shared__ __align__(16) unsigned char smRaw[2 * PANEL_BYTES + CPCN_BYTES];
    unsigned char* Bs0  = smRaw;
    unsigned char* Bs1  = smRaw + PANEL_BYTES;
    float*         smCp = (float*)(smRaw + 2 * PANEL_BYTES);   // [1024]
    float*         smCn = smCp + 1024;                          // [1024]

    const int tid = threadIdx.x;
    const int w   = tid >> 6;
    const int l   = tid & 63;
    const int lq  = l >> 4;          // quad 0..3
    const int lm  = l & 15;
    const int row0 = blockIdx.x * 128;
    const int col0 = blockIdx.y * 1024;
    const int nPanels = 16;

    const int wr = (w >> 1) * 64;    // wave's row half
    const int wc = (w & 1) * 32;     // wave's col half within 64-col panel

    // staging source-slot swizzle: slot = (l&15) with low2 ^= (l>>4)
    const int sl = (l & 12) | ((l ^ (l >> 4)) & 3);

    // prologue DMAs: panel 0 + cpos/cneg slabs (wave w -> 1 KB slice each)
    stage_panel(e2b + (size_t)col0 * DDIM, Bs0, w, l, sl);
    g2lds16(cpos + col0 + w * 256 + l * 4, smCp + w * 256);
    g2lds16(cneg + col0 + w * 256 + l * 4, smCn + w * 256);

    // A fragments straight from global: row = row0+wr+i*16+lm,
    // elems [k4*32 + lq*8, +8). L2-resident (e1b = 2 MB, pre-scaled by -2).
    const ushort_t* aG = e1b + (size_t)(row0 + wr + lm) * DDIM + lq * 8;
    short8 afr[4][4];                // [i][k4]: 64 regs, K=128 resident
    #pragma unroll
    for (int i = 0; i < 4; ++i)
        #pragma unroll
        for (int k4 = 0; k4 < 4; ++k4)
            afr[i][k4] = *(const short8*)(aG + i * 16 * DDIM + k4 * 32);

    // B fragment read base: row R = wc + j*16 + lm; byte addr =
    //   (R>>2)*1056 + (R&3)*256 + (k4*4 + (lq^(R&3)))*16
    // (lane-constant base; + j*4*1056 + k4*64). lq^(lm&3) = swizzle inverse.
    const unsigned char* bLane = Bs0
        + ((wc >> 2) + (lm >> 2)) * CHUNK_PITCH
        + (lm & 3) * 256 + ((lq ^ (lm & 3)) * 16);

    float pm[4][4], nm[4][4];        // [i][r]: local row = wr + i*16 + lq*4 + r
    #pragma unroll
    for (int i = 0; i < 4; ++i)
        #pragma unroll
        for (int r = 0; r < 4; ++r) { pm[i][r] = -SENT; nm[i][r] = SENT; }

    __syncthreads();   // full drain: panel 0 + cpcn + afr all resident

    for (int p = 0; p < nPanels; ++p) {
        // WAR barrier: all waves done READING panel p-1 -> its parity
        // buffer may now be overwritten by stage(p+1). (p=0: prologue
        // __syncthreads already synced.)
        if (p) __builtin_amdgcn_s_barrier();

        if (p + 1 < nPanels) {
            // issue next panel's DMA; vmcnt queue = [stage(p):4, stage(p+1):4]
            stage_panel(e2b + (size_t)(col0 + (p + 1) * 64) * DDIM,
                        (p & 1) ? Bs0 : Bs1, w, l, sl);
            // retire exactly OWN stage(p) (4 oldest); stage(p+1) in flight
            asm volatile("s_waitcnt vmcnt(4)" ::: "memory");
        } else {
            asm volatile("s_waitcnt vmcnt(0)" ::: "memory");
        }
        // RAW barrier: every wave has retired ITS stage(p) loads, so the
        // whole panel p (all 4 waves' rows) is resident before any read.
        __builtin_amdgcn_s_barrier();

        const unsigned char* bl = bLane + (p & 1) * PANEL_BYTES;

        f32x4 accA[4], accB[4];      // j=0 / j=1 accumulators (32 regs)
        #pragma unroll
        for (int i = 0; i < 4; ++i) {
            accA[i] = (f32x4){0.f, 0.f, 0.f, 0.f};
            accB[i] = (f32x4){0.f, 0.f, 0.f, 0.f};
        }

        #pragma unroll
        for (int k4 = 0; k4 < 4; ++k4) {
            const short8 b0 = *(const short8*)(bl + k4 * 64);
            const short8 b1 = *(const short8*)(bl + 4 * CHUNK_PITCH + k4 * 64);
            #pragma unroll
            for (int i = 0; i < 4; ++i)
                accA[i] = __builtin_amdgcn_mfma_f32_16x16x32_bf16(
                              afr[i][k4], b0, accA[i], 0, 0, 0);
            #pragma unroll
            for (int i = 0; i < 4; ++i)
                accB[i] = __builtin_amdgcn_mfma_f32_16x16x32_bf16(
                              afr[i][k4], b1, accB[i], 0, 0, 0);
        }

        // epilogue: acc = -2*dot; colterm from LDS (lgkm only -> vmcnt
        // ledger stays pure). Paired so clang fuses v_max3/v_min3.
        {
            const int lcb = p * 64 + wc + lm;            // C/D: col = lane&15
            const float cp0 = smCp[lcb],      cn0 = smCn[lcb];
            const float cp1 = smCp[lcb + 16], cn1 = smCn[lcb + 16];
            #pragma unroll
            for (int i = 0; i < 4; ++i)
                #pragma unroll
                for (int r = 0; r < 4; ++r) {
                    const float d0 = accA[i][r];
                    const float d1 = accB[i][r];
                    pm[i][r] = fmaxf(fmaxf(pm[i][r], d0 + cp0), d1 + cp1);
                    nm[i][r] = fminf(fminf(nm[i][r], d0 + cn0), d1 + cn1);
                }
        }
    }

    // intra-wave: reduce across the 16 column-lanes (rows fixed per (lq,r))
    #pragma unroll
    for (int m = 1; m < 16; m <<= 1) {
        #pragma unroll
        for (int i = 0; i < 4; ++i)
            #pragma unroll
            for (int r = 0; r < 4; ++r) {
                pm[i][r] = fmaxf(pm[i][r], __shfl_xor(pm[i][r], m, 64));
                nm[i][r] = fminf(nm[i][r], __shfl_xor(nm[i][r], m, 64));
            }
    }

    // cross-wave: pairs (0,1),(2,3) share rows over complementary col halves.
    // Overlay on Bs0 (panel 15 lives in Bs1; Bs0's readers done at p=15's
    // WAR barrier). Even waves read only after the __syncthreads below.
    float* smP = (float*)smRaw;            // [128]
    float* smN = smP + 128;                // [128]
    if ((w & 1) == 1 && lm == 0) {
        #pragma unroll
        for (int i = 0; i < 4; ++i)
            #pragma unroll
            for (int r = 0; r < 4; ++r) {
                int lr = wr + i * 16 + lq * 4 + r;
                smP[lr] = pm[i][r];
                smN[lr] = nm[i][r];
            }
    }
    __syncthreads();
    if ((w & 1) == 0 && lm == 0) {
        #pragma unroll
        for (int i = 0; i < 4; ++i)
            #pragma unroll
            for (int r = 0; r < 4; ++r) {
                int lr = wr + i * 16 + lq * 4 + r;   // C/D: row = quad*4+reg
                smP[lr] = fmaxf(pm[i][r], smP[lr]);
                smN[lr] = fminf(nm[i][r], smN[lr]);
            }
    }
    __syncthreads();
    if (tid < 128) {                       // coalesced partial store
        pmp[(size_t)blockIdx.y * B + row0 + tid] = smP[tid];
        nmp[(size_t)blockIdx.y * B + row0 + tid] = smN[tid];
    }
}

// ---- kernel 3: per-row combine + hinge; atomic partials; last block divides ----
__global__ void reduce_kernel(const float* __restrict__ pmp, const float* __restrict__ nmp,
                              const float* __restrict__ rowterm, const int* __restrict__ target,
                              float* __restrict__ redsum, int* __restrict__ ticket,
                              float* __restrict__ out, int B) {
    int row = blockIdx.x * blockDim.x + threadIdx.x;    // 32 x 256 = 8192
    float s = 0.f, c = 0.f;
    {
        float pmv = -SENT, nmv = SENT;
        #pragma unroll
        for (int sp = 0; sp < SPLITS; ++sp) {
            pmv = fmaxf(pmv, pmp[(size_t)sp * B + row]);
            nmv = fminf(nmv, nmp[(size_t)sp * B + row]);
        }
        float rt = rowterm[row];
        float dp = sqrtf(fmaxf(rt + pmv, 0.f));
        float dn = sqrtf(fmaxf(rt + nmv, 0.f));
        if (target[row] == 1) {
            s = fmaxf(dp - dn + MARGIN, 0.f);
            c = 1.f;
        }
    }
    #pragma unroll
    for (int off = 32; off > 0; off >>= 1) {
        s += __shfl_down(s, off, 64);
        c += __shfl_down(c, off, 64);
    }
    __shared__ float ls[4], lc[4];
    int wv = threadIdx.x >> 6, ln = threadIdx.x & 63;
    if (ln == 0) { ls[wv] = s; lc[wv] = c; }
    __syncthreads();
    if (threadIdx.x == 0) {
        float ss = ls[0] + ls[1] + ls[2] + ls[3];
        float cc = lc[0] + lc[1] + lc[2] + lc[3];
        atomicAdd(&redsum[0], ss);
        atomicAdd(&redsum[1], cc);
        __threadfence();
        int done = atomicAdd(ticket, 1);
        if (done == (int)gridDim.x - 1) {
            __threadfence();
            float fs = __hip_atomic_load(&redsum[0], __ATOMIC_RELAXED, __HIP_MEMORY_SCOPE_AGENT);
            float fc = __hip_atomic_load(&redsum[1], __ATOMIC_RELAXED, __HIP_MEMORY_SCOPE_AGENT);
            out[0] = fs / fc;
        }
    }
}

extern "C" void kernel_launch(void* const* d_in, const int* in_sizes, int n_in,
                              void* d_out, int out_size, void* d_ws, size_t ws_size,
                              hipStream_t stream) {
    const float* e1     = (const float*)d_in[0];
    const float* e2     = (const float*)d_in[1];
    const int*   target = (const int*)d_in[2];
    float* out = (float*)d_out;
    const int B = in_sizes[2];                       // 8192

    // ws layout: e1b | e2b | rowterm | cpos | cneg | pmp | nmp | redsum | ticket
    char* p = (char*)d_ws;
    ushort_t* e1b  = (ushort_t*)p;   p += (size_t)B * DDIM * 2;   // 2 MB (scaled by -2)
    ushort_t* e2b  = (ushort_t*)p;   p += (size_t)B * DDIM * 2;   // 2 MB
    float* rowterm = (float*)p;      p += (size_t)B * 4;
    float* cpos    = (float*)p;      p += (size_t)B * 4;
    float* cneg    = (float*)p;      p += (size_t)B * 4;
    float* pmp     = (float*)p;      p += (size_t)SPLITS * B * 4; // 256 KB
    float* nmp     = (float*)p;      p += (size_t)SPLITS * B * 4; // 256 KB
    float* redsum  = (float*)p;      p += 2 * 4;
    int*   ticket  = (int*)p;

    {   // prep: 8 lanes/row, 32 rows/block -> 2B/32 = 512 blocks
        int blocks = (2 * B) / 32;
        prep_kernel<<<blocks, 256, 0, stream>>>(e1, e2, target, e1b, e2b,
                                                rowterm, cpos, cneg,
                                                redsum, ticket, B);
    }
    {   // 64 row-blocks x 8 col-splits = 512 blocks; 41.8 KB LDS, 3 waves/SIMD
        dim3 grid(B / 128, SPLITS);
        tile_kernel<<<grid, 256, 0, stream>>>(e1b, e2b, cpos, cneg, pmp, nmp, B);
    }
    reduce_kernel<<<32, 256, 0, stream>>>(pmp, nmp, rowterm, target,
                                          redsum, ticket, out, B);
}